// Round 3
// baseline (585.710 us; speedup 1.0000x reference)
//
#include <hip/hip_runtime.h>
#include <hip/hip_fp16.h>

// ---------------- CSR construction (unchanged) ----------------

__global__ void count_kernel(const int* __restrict__ dst, int* __restrict__ counts, int E) {
    int e = blockIdx.x * 256 + threadIdx.x;
    if (e < E) atomicAdd(&counts[dst[e]], 1);
}

__global__ void scan_local(const int* __restrict__ counts, int* __restrict__ rowptr,
                           int* __restrict__ bsums, float* __restrict__ dinv, int N) {
    __shared__ int sm[256];
    int t = threadIdx.x;
    int gid = blockIdx.x * 256 + t;
    int v = (gid < N) ? counts[gid] : 0;
    if (gid < N) dinv[gid] = rsqrtf((float)v + 1.0f);
    int x = v;
    sm[t] = x; __syncthreads();
    for (int off = 1; off < 256; off <<= 1) {
        int y = (t >= off) ? sm[t - off] : 0;
        __syncthreads();
        x += y; sm[t] = x; __syncthreads();
    }
    if (gid < N) rowptr[gid] = x - v;
    if (t == 255) bsums[blockIdx.x] = x;
}

__global__ void scan_bsums(int* bsums, int nb) {
    __shared__ int sm[512];
    int t = threadIdx.x;
    int v = (t < nb) ? bsums[t] : 0;
    int x = v;
    sm[t] = x; __syncthreads();
    for (int off = 1; off < 512; off <<= 1) {
        int y = (t >= off) ? sm[t - off] : 0;
        __syncthreads();
        x += y; sm[t] = x; __syncthreads();
    }
    if (t < nb) bsums[t] = x - v;
}

__global__ void scan_add(int* __restrict__ rowptr, const int* __restrict__ bsums, int N) {
    int gid = blockIdx.x * 256 + threadIdx.x;
    if (gid < N) rowptr[gid] += bsums[blockIdx.x];
}

__global__ void fill_kernel(const int* __restrict__ src, const int* __restrict__ dst,
                            const int* __restrict__ rowptr, int* __restrict__ fillc,
                            const float* __restrict__ dinv,
                            int2* __restrict__ edges, int E) {
    int e = blockIdx.x * 256 + threadIdx.x;
    if (e < E) {
        int d = dst[e];
        int s = src[e];
        int pos = rowptr[d] + atomicAdd(&fillc[d], 1);
        edges[pos] = make_int2(s, __float_as_int(dinv[s]));
    }
}

// ---------------- fp32 -> fp16 cast (X -> X16) ----------------

__global__ void cast_kernel(const float* __restrict__ X, __half* __restrict__ X16, int total4) {
    int i = blockIdx.x * 256 + threadIdx.x;
    if (i < total4) {
        float4 v = *(const float4*)&X[(size_t)i * 4];
        __half2 h0 = __floats2half2_rn(v.x, v.y);
        __half2 h1 = __floats2half2_rn(v.z, v.w);
        uint2 pk = make_uint2(*(unsigned int*)&h0, *(unsigned int*)&h1);
        *(uint2*)&X16[(size_t)i * 4] = pk;
    }
}

// ---------------- fp16 gather helper: 8 halves (16B) scaled-accumulate ----------------

__device__ __forceinline__ void acc8(float* a, float4 raw, float f) {
    const __half2* hp = (const __half2*)&raw;
#pragma unroll
    for (int i = 0; i < 4; ++i) {
        float2 v = __half22float2(hp[i]);
        a[2 * i]     = fmaf(f, v.x, a[2 * i]);
        a[2 * i + 1] = fmaf(f, v.y, a[2 * i + 1]);
    }
}

// ------- agg1: aggregate raw X16, then h1 = relu(agg @ W1 + b1), write fp16 -------
// Gather: 8 groups of 8 lanes; lane holds halves cb..cb+7 (cb=(lane&7)*8).
// One global_load_dwordx4 (16B = 8 halves) x 8 lanes = one full 128B row;
// one load instruction services 8 edges (one per group). Row = 2 cache lines
// (was 4 in fp32) => halves the line-service cost that R2 proved is the floor.

__global__ void agg1_kernel(const __half* __restrict__ X16, const int2* __restrict__ edges,
                            const int* __restrict__ rowptr, const int* __restrict__ counts,
                            const float* __restrict__ dinv, const float* __restrict__ W1,
                            const float* __restrict__ b1, __half* __restrict__ H1, int N) {
    __shared__ float Wl[64 * 64];
    __shared__ float hb[4][2][64];
    int tid = threadIdx.x;
    for (int i = tid; i < 4096; i += 256) Wl[i] = W1[i];
    __syncthreads();
    int lane = tid & 63, wave = tid >> 6;
    int g = lane >> 3;
    int cb = (lane & 7) * 8;
    const __half* Xcb = X16 + cb;
    float bb = b1[lane];
    int NP = (N + 1) >> 1;
    int p0 = blockIdx.x * 4 + wave;
    int pstr = gridDim.x * 4;
    for (int p = p0; p < NP; p += pstr) {
        int vA = 2 * p, vB = 2 * p + 1;
        bool hasB = vB < N;
        int startA = __builtin_amdgcn_readfirstlane(rowptr[vA]);
        int cntA   = __builtin_amdgcn_readfirstlane(counts[vA]);
        int startB = hasB ? __builtin_amdgcn_readfirstlane(rowptr[vB]) : 0;
        int cntB   = hasB ? __builtin_amdgcn_readfirstlane(counts[vB]) : 0;
        float dvA = dinv[vA];
        float dvB = hasB ? dinv[vB] : 0.f;
        int vBs = hasB ? vB : vA;
        // self-loop rows: issue early, consumed after the edge loop
        float4 srA = *(const float4*)&Xcb[(size_t)vA * 64];
        float4 srB = *(const float4*)&Xcb[(size_t)vBs * 64];
        float aA[8] = {0.f, 0.f, 0.f, 0.f, 0.f, 0.f, 0.f, 0.f};
        float aB[8] = {0.f, 0.f, 0.f, 0.f, 0.f, 0.f, 0.f, 0.f};
        int cntM = max(cntA, cntB);
        for (int base = 0; base < cntM; base += 64) {
            int nbA = min(64, cntA - base);
            int nbB = min(64, cntB - base);
            int idxA = 0, idxB = 0; float dsA = 0.f, dsB = 0.f;
            if (lane < nbA) { int2 e = edges[startA + base + lane]; idxA = e.x; dsA = __int_as_float(e.y); }
            if (lane < nbB) { int2 e = edges[startB + base + lane]; idxB = e.x; dsB = __int_as_float(e.y); }
            int nbM = max(nbA, nbB);
            int nt = (nbM + 7) >> 3;
            nt = (nt + 1) & ~1;           // even for unroll-2; nt<=8 so shfl idx <= 63
            for (int t = 0; t < nt; t += 2) {
                int l0 = 8 * t + g;
                int l1 = l0 + 8;
                int   sA0 = __shfl(idxA, l0); float fA0 = __shfl(dsA, l0);
                int   sA1 = __shfl(idxA, l1); float fA1 = __shfl(dsA, l1);
                int   sB0 = __shfl(idxB, l0); float fB0 = __shfl(dsB, l0);
                int   sB1 = __shfl(idxB, l1); float fB1 = __shfl(dsB, l1);
                float4 rA0 = *(const float4*)&Xcb[(size_t)sA0 * 64];
                float4 rA1 = *(const float4*)&Xcb[(size_t)sA1 * 64];
                float4 rB0 = *(const float4*)&Xcb[(size_t)sB0 * 64];
                float4 rB1 = *(const float4*)&Xcb[(size_t)sB1 * 64];
                acc8(aA, rA0, fA0);
                acc8(aA, rA1, fA1);
                acc8(aB, rB0, fB0);
                acc8(aB, rB1, fB1);
            }
        }
        // cross-group reduce (groups live in lane bits 3..5)
#pragma unroll
        for (int i = 0; i < 8; ++i) {
            aA[i] += __shfl_xor(aA[i], 8);  aA[i] += __shfl_xor(aA[i], 16); aA[i] += __shfl_xor(aA[i], 32);
            aB[i] += __shfl_xor(aB[i], 8);  aB[i] += __shfl_xor(aB[i], 16); aB[i] += __shfl_xor(aB[i], 32);
        }
        // self-loop (added once, post-reduce) then outer dinv scale
        acc8(aA, srA, dvA);
        acc8(aB, srB, dvB);
#pragma unroll
        for (int i = 0; i < 8; ++i) { aA[i] *= dvA; aB[i] *= dvB; }
        // transpose to feature=lane via per-wave LDS
        if (lane < 8) {
            *(float4*)&hb[wave][0][cb]     = make_float4(aA[0], aA[1], aA[2], aA[3]);
            *(float4*)&hb[wave][0][cb + 4] = make_float4(aA[4], aA[5], aA[6], aA[7]);
            *(float4*)&hb[wave][1][cb]     = make_float4(aB[0], aB[1], aB[2], aB[3]);
            *(float4*)&hb[wave][1][cb + 4] = make_float4(aB[4], aB[5], aB[6], aB[7]);
        }
        float sAl = hb[wave][0][lane];
        float sBl = hb[wave][1][lane];
        // h1 = relu(agg @ W1 + b1)
        float yA = bb, yB = bb;
#pragma unroll 8
        for (int k = 0; k < 64; ++k) {
            float w = Wl[k * 64 + lane];
            yA = fmaf(__shfl(sAl, k), w, yA);
            yB = fmaf(__shfl(sBl, k), w, yB);
        }
        yA = fmaxf(yA, 0.f); yB = fmaxf(yB, 0.f);
        H1[(size_t)vA * 64 + lane] = __float2half(yA);
        if (hasB) H1[(size_t)vB * 64 + lane] = __float2half(yB);
    }
}

// ------- agg2: aggregate h1(fp16), then W2+b2 relu, dW1+db1 relu, dW2+db2 -------

__global__ void agg2_kernel(const __half* __restrict__ H1, const int2* __restrict__ edges,
                            const int* __restrict__ rowptr, const int* __restrict__ counts,
                            const float* __restrict__ dinv, const float* __restrict__ W2,
                            const float* __restrict__ b2, const float* __restrict__ dW1,
                            const float* __restrict__ db1, const float* __restrict__ dW2,
                            const float* __restrict__ db2, float* __restrict__ out, int N) {
    __shared__ float W2l[64 * 64];
    __shared__ float D1[64 * 64];
    __shared__ float Wh[64 * 16];
    __shared__ float hb[4][2][64];
    int tid = threadIdx.x;
    for (int i = tid; i < 4096; i += 256) W2l[i] = W2[i];
    for (int i = tid; i < 4096; i += 256) D1[i] = dW1[i];
    for (int i = tid; i < 1024; i += 256) Wh[i] = dW2[i];
    __syncthreads();
    int lane = tid & 63, wave = tid >> 6;
    int g = lane >> 3;
    int cb = (lane & 7) * 8;
    const __half* Hcb = H1 + cb;
    int c = lane & 15, part = lane >> 4;
    float bb2 = b2[lane];
    float bb1 = db1[lane];
    float ob  = db2[c];
    int NP = (N + 1) >> 1;
    int p0 = blockIdx.x * 4 + wave;
    int pstr = gridDim.x * 4;
    for (int p = p0; p < NP; p += pstr) {
        int vA = 2 * p, vB = 2 * p + 1;
        bool hasB = vB < N;
        int startA = __builtin_amdgcn_readfirstlane(rowptr[vA]);
        int cntA   = __builtin_amdgcn_readfirstlane(counts[vA]);
        int startB = hasB ? __builtin_amdgcn_readfirstlane(rowptr[vB]) : 0;
        int cntB   = hasB ? __builtin_amdgcn_readfirstlane(counts[vB]) : 0;
        float dvA = dinv[vA];
        float dvB = hasB ? dinv[vB] : 0.f;
        int vBs = hasB ? vB : vA;
        float4 srA = *(const float4*)&Hcb[(size_t)vA * 64];
        float4 srB = *(const float4*)&Hcb[(size_t)vBs * 64];
        float aA[8] = {0.f, 0.f, 0.f, 0.f, 0.f, 0.f, 0.f, 0.f};
        float aB[8] = {0.f, 0.f, 0.f, 0.f, 0.f, 0.f, 0.f, 0.f};
        int cntM = max(cntA, cntB);
        for (int base = 0; base < cntM; base += 64) {
            int nbA = min(64, cntA - base);
            int nbB = min(64, cntB - base);
            int idxA = 0, idxB = 0; float dsA = 0.f, dsB = 0.f;
            if (lane < nbA) { int2 e = edges[startA + base + lane]; idxA = e.x; dsA = __int_as_float(e.y); }
            if (lane < nbB) { int2 e = edges[startB + base + lane]; idxB = e.x; dsB = __int_as_float(e.y); }
            int nbM = max(nbA, nbB);
            int nt = (nbM + 7) >> 3;
            nt = (nt + 1) & ~1;
            for (int t = 0; t < nt; t += 2) {
                int l0 = 8 * t + g;
                int l1 = l0 + 8;
                int   sA0 = __shfl(idxA, l0); float fA0 = __shfl(dsA, l0);
                int   sA1 = __shfl(idxA, l1); float fA1 = __shfl(dsA, l1);
                int   sB0 = __shfl(idxB, l0); float fB0 = __shfl(dsB, l0);
                int   sB1 = __shfl(idxB, l1); float fB1 = __shfl(dsB, l1);
                float4 rA0 = *(const float4*)&Hcb[(size_t)sA0 * 64];
                float4 rA1 = *(const float4*)&Hcb[(size_t)sA1 * 64];
                float4 rB0 = *(const float4*)&Hcb[(size_t)sB0 * 64];
                float4 rB1 = *(const float4*)&Hcb[(size_t)sB1 * 64];
                acc8(aA, rA0, fA0);
                acc8(aA, rA1, fA1);
                acc8(aB, rB0, fB0);
                acc8(aB, rB1, fB1);
            }
        }
#pragma unroll
        for (int i = 0; i < 8; ++i) {
            aA[i] += __shfl_xor(aA[i], 8);  aA[i] += __shfl_xor(aA[i], 16); aA[i] += __shfl_xor(aA[i], 32);
            aB[i] += __shfl_xor(aB[i], 8);  aB[i] += __shfl_xor(aB[i], 16); aB[i] += __shfl_xor(aB[i], 32);
        }
        acc8(aA, srA, dvA);
        acc8(aB, srB, dvB);
#pragma unroll
        for (int i = 0; i < 8; ++i) { aA[i] *= dvA; aB[i] *= dvB; }
        if (lane < 8) {
            *(float4*)&hb[wave][0][cb]     = make_float4(aA[0], aA[1], aA[2], aA[3]);
            *(float4*)&hb[wave][0][cb + 4] = make_float4(aA[4], aA[5], aA[6], aA[7]);
            *(float4*)&hb[wave][1][cb]     = make_float4(aB[0], aB[1], aB[2], aB[3]);
            *(float4*)&hb[wave][1][cb + 4] = make_float4(aB[4], aB[5], aB[6], aB[7]);
        }
        float sAl = hb[wave][0][lane];
        float sBl = hb[wave][1][lane];
        // h2 = relu(agg @ W2 + b2)
        float hA = bb2, hB = bb2;
#pragma unroll 8
        for (int k = 0; k < 64; ++k) {
            float w = W2l[k * 64 + lane];
            hA = fmaf(__shfl(sAl, k), w, hA);
            hB = fmaf(__shfl(sBl, k), w, hB);
        }
        hA = fmaxf(hA, 0.f); hB = fmaxf(hB, 0.f);
        // a = relu(h2 @ dW1 + db1)
        float aAv = bb1, aBv = bb1;
#pragma unroll 8
        for (int k = 0; k < 64; ++k) {
            float w = D1[k * 64 + lane];
            aAv = fmaf(__shfl(hA, k), w, aAv);
            aBv = fmaf(__shfl(hB, k), w, aBv);
        }
        aAv = fmaxf(aAv, 0.f); aBv = fmaxf(aBv, 0.f);
        // o = a @ dW2 + db2 (split-16 partial sums, reduced across 4 parts)
        float oA = 0.f, oB = 0.f;
#pragma unroll 8
        for (int kk = 0; kk < 16; ++kk) {
            float w = Wh[(part * 16 + kk) * 16 + c];
            oA = fmaf(__shfl(aAv, part * 16 + kk), w, oA);
            oB = fmaf(__shfl(aBv, part * 16 + kk), w, oB);
        }
        oA += __shfl_xor(oA, 16); oA += __shfl_xor(oA, 32);
        oB += __shfl_xor(oB, 16); oB += __shfl_xor(oB, 32);
        if (lane < 16) {
            out[(size_t)vA * 16 + lane] = oA + ob;
            if (hasB) out[(size_t)vB * 16 + lane] = oB + ob;
        }
    }
}

// ---------------- launch ----------------

extern "C" void kernel_launch(void* const* d_in, const int* in_sizes, int n_in,
                              void* d_out, int out_size, void* d_ws, size_t ws_size,
                              hipStream_t stream) {
    const float* x   = (const float*)d_in[0];
    const int*   ei  = (const int*)d_in[1];
    const float* W1  = (const float*)d_in[2];
    const float* b1  = (const float*)d_in[3];
    const float* W2  = (const float*)d_in[4];
    const float* b2  = (const float*)d_in[5];
    const float* dW1 = (const float*)d_in[6];
    const float* db1 = (const float*)d_in[7];
    const float* dW2 = (const float*)d_in[8];
    const float* db2 = (const float*)d_in[9];
    float* out = (float*)d_out;

    int N = in_sizes[0] / 64;
    int E = in_sizes[1] / 2;
    const int* src = ei;
    const int* dst = ei + E;

    size_t off = 0;
    auto alloc = [&](size_t bytes) {
        void* p = (char*)d_ws + off;
        off += (bytes + 511) & ~(size_t)511;
        return p;
    };
    int Npad = (N + 127) & ~127;
    int*    counts = (int*)alloc((size_t)Npad * 8);     // [counts | fillc]
    int*    fillc  = counts + Npad;
    int*    rowptr = (int*)alloc((size_t)N * 4);
    int*    bsums  = (int*)alloc(512 * 4);
    int2*   edges  = (int2*)alloc((size_t)E * 8);
    float*  dinv   = (float*)alloc((size_t)N * 4);
    __half* x16    = (__half*)alloc((size_t)N * 64 * 2);
    __half* h1     = (__half*)alloc((size_t)N * 64 * 2);

    hipMemsetAsync(counts, 0, (size_t)Npad * 8, stream);

    int nbN = (N + 255) / 256;
    int nbE = (E + 255) / 256;
    int nbC = (N * 16 + 255) / 256;

    count_kernel<<<nbE, 256, 0, stream>>>(dst, counts, E);
    scan_local<<<nbN, 256, 0, stream>>>(counts, rowptr, bsums, dinv, N);
    scan_bsums<<<1, 512, 0, stream>>>(bsums, nbN);
    scan_add<<<nbN, 256, 0, stream>>>(rowptr, bsums, N);
    fill_kernel<<<nbE, 256, 0, stream>>>(src, dst, rowptr, fillc, dinv, edges, E);
    cast_kernel<<<nbC, 256, 0, stream>>>(x, x16, N * 16);

    agg1_kernel<<<2048, 256, 0, stream>>>(x16, edges, rowptr, counts, dinv, W1, b1, h1, N);
    agg2_kernel<<<2048, 256, 0, stream>>>(h1, edges, rowptr, counts, dinv, W2, b2,
                                          dW1, db1, dW2, db2, out, N);
}

// Round 4
// 506.629 us; speedup vs baseline: 1.1561x; 1.1561x over previous
//
#include <hip/hip_runtime.h>
#include <hip/hip_fp16.h>

// ---------------- CSR construction (unchanged) ----------------

__global__ void count_kernel(const int* __restrict__ dst, int* __restrict__ counts, int E) {
    int e = blockIdx.x * 256 + threadIdx.x;
    if (e < E) atomicAdd(&counts[dst[e]], 1);
}

__global__ void scan_local(const int* __restrict__ counts, int* __restrict__ rowptr,
                           int* __restrict__ bsums, float* __restrict__ dinv, int N) {
    __shared__ int sm[256];
    int t = threadIdx.x;
    int gid = blockIdx.x * 256 + t;
    int v = (gid < N) ? counts[gid] : 0;
    if (gid < N) dinv[gid] = rsqrtf((float)v + 1.0f);
    int x = v;
    sm[t] = x; __syncthreads();
    for (int off = 1; off < 256; off <<= 1) {
        int y = (t >= off) ? sm[t - off] : 0;
        __syncthreads();
        x += y; sm[t] = x; __syncthreads();
    }
    if (gid < N) rowptr[gid] = x - v;
    if (t == 255) bsums[blockIdx.x] = x;
}

__global__ void scan_bsums(int* bsums, int nb) {
    __shared__ int sm[512];
    int t = threadIdx.x;
    int v = (t < nb) ? bsums[t] : 0;
    int x = v;
    sm[t] = x; __syncthreads();
    for (int off = 1; off < 512; off <<= 1) {
        int y = (t >= off) ? sm[t - off] : 0;
        __syncthreads();
        x += y; sm[t] = x; __syncthreads();
    }
    if (t < nb) bsums[t] = x - v;
}

__global__ void scan_add(int* __restrict__ rowptr, const int* __restrict__ bsums, int N) {
    int gid = blockIdx.x * 256 + threadIdx.x;
    if (gid < N) rowptr[gid] += bsums[blockIdx.x];
}

__global__ void fill_kernel(const int* __restrict__ src, const int* __restrict__ dst,
                            const int* __restrict__ rowptr, int* __restrict__ fillc,
                            const float* __restrict__ dinv,
                            int2* __restrict__ edges, int E) {
    int e = blockIdx.x * 256 + threadIdx.x;
    if (e < E) {
        int d = dst[e];
        int s = src[e];
        int pos = rowptr[d] + atomicAdd(&fillc[d], 1);
        edges[pos] = make_int2(s, __float_as_int(dinv[s]));
    }
}

// ---------------- xw = X @ W1 -> fp16 (fused cast) ----------------

__global__ void __launch_bounds__(128)
gemm64_kernel(const float* __restrict__ X, const float* __restrict__ W,
              __half* __restrict__ out, int N) {
    __shared__ float Wl[64 * 64];
    __shared__ float hbuf[2][256];
    int tid = threadIdx.x;
    int lane = tid & 63;
    for (int i = tid; i < 4096; i += 128) Wl[i] = W[i];
    __syncthreads();
    int wi = __builtin_amdgcn_readfirstlane(tid >> 6);
    float* hb = &hbuf[wi][0];
    int g0 = blockIdx.x * 2 + wi;
    int ng = gridDim.x * 2;
    int NG = (N + 3) >> 2;
    for (int g = g0; g < NG; g += ng) {
        int v0 = g * 4;
        float x0 = (v0 + 0 < N) ? X[(size_t)(v0 + 0) * 64 + lane] : 0.f;
        float x1 = (v0 + 1 < N) ? X[(size_t)(v0 + 1) * 64 + lane] : 0.f;
        float x2 = (v0 + 2 < N) ? X[(size_t)(v0 + 2) * 64 + lane] : 0.f;
        float x3 = (v0 + 3 < N) ? X[(size_t)(v0 + 3) * 64 + lane] : 0.f;
        *(float4*)&hb[lane * 4] = make_float4(x0, x1, x2, x3);
        float y0 = 0.f, y1 = 0.f, y2 = 0.f, y3 = 0.f;
#pragma unroll 8
        for (int k = 0; k < 64; ++k) {
            float4 hk = *(const float4*)&hb[k * 4];
            float w = Wl[k * 64 + lane];
            y0 = fmaf(hk.x, w, y0);
            y1 = fmaf(hk.y, w, y1);
            y2 = fmaf(hk.z, w, y2);
            y3 = fmaf(hk.w, w, y3);
        }
        if (v0 + 0 < N) out[(size_t)(v0 + 0) * 64 + lane] = __float2half(y0);
        if (v0 + 1 < N) out[(size_t)(v0 + 1) * 64 + lane] = __float2half(y1);
        if (v0 + 2 < N) out[(size_t)(v0 + 2) * 64 + lane] = __float2half(y2);
        if (v0 + 3 < N) out[(size_t)(v0 + 3) * 64 + lane] = __float2half(y3);
    }
}

// ---- fp16 gather helper: 4 halves (8B) scaled-accumulate into fp32 ----

__device__ __forceinline__ void acc4(float* a, uint2 raw, float f) {
    float2 v0 = __half22float2(*(const __half2*)&raw.x);
    float2 v1 = __half22float2(*(const __half2*)&raw.y);
    a[0] = fmaf(f, v0.x, a[0]);
    a[1] = fmaf(f, v0.y, a[1]);
    a[2] = fmaf(f, v1.x, a[2]);
    a[3] = fmaf(f, v1.y, a[3]);
}

// ------- layer1 agg + @W2 (R2 structure, fp16 gather/output) -------
// 4 groups of 16 lanes; lane holds features cb..cb+3 (cb=(lane&15)*4) as fp16.
// One uint2 load = 4 halves; a 16-lane group covers one 128B row = 2 cache
// lines (was 4 in fp32) => halves the L2-fill line traffic that R1/R2 pinned
// at ~1.2 TB/s. Structure (LDS, MM count, grouping) identical to R2.

__global__ void agg_mm_kernel(const __half* __restrict__ XW, const int2* __restrict__ edges,
                              const int* __restrict__ rowptr, const int* __restrict__ counts,
                              const float* __restrict__ dinv, const float* __restrict__ bias,
                              const float* __restrict__ W2, __half* __restrict__ Y, int N) {
    __shared__ float Wl[64 * 64];
    __shared__ float hb[4][2][64];
    int tid = threadIdx.x;
    for (int i = tid; i < 4096; i += 256) Wl[i] = W2[i];
    __syncthreads();
    int lane = tid & 63, wave = tid >> 6;
    int g = lane >> 4;
    int cb = (lane & 15) * 4;
    const __half* Xcb = XW + cb;
    float4 bb4 = *(const float4*)&bias[cb];
    int NP = (N + 1) >> 1;
    int p0 = blockIdx.x * 4 + wave;
    int pstr = gridDim.x * 4;
    for (int p = p0; p < NP; p += pstr) {
        int vA = 2 * p, vB = 2 * p + 1;
        bool hasB = vB < N;
        int startA = __builtin_amdgcn_readfirstlane(rowptr[vA]);
        int cntA   = __builtin_amdgcn_readfirstlane(counts[vA]);
        int startB = hasB ? __builtin_amdgcn_readfirstlane(rowptr[vB]) : 0;
        int cntB   = hasB ? __builtin_amdgcn_readfirstlane(counts[vB]) : 0;
        float dvA = dinv[vA];
        float dvB = hasB ? dinv[vB] : 0.f;
        int vBs = hasB ? vB : vA;
        uint2 srA = *(const uint2*)&Xcb[(size_t)vA * 64];
        uint2 srB = *(const uint2*)&Xcb[(size_t)vBs * 64];
        float aA[4] = {0.f, 0.f, 0.f, 0.f};
        float aB[4] = {0.f, 0.f, 0.f, 0.f};
        int cntM = max(cntA, cntB);
        for (int base = 0; base < cntM; base += 64) {
            int nbA = min(64, cntA - base);
            int nbB = min(64, cntB - base);
            int idxA = 0, idxB = 0; float dsA = 0.f, dsB = 0.f;
            if (lane < nbA) { int2 e = edges[startA + base + lane]; idxA = e.x; dsA = __int_as_float(e.y); }
            if (lane < nbB) { int2 e = edges[startB + base + lane]; idxB = e.x; dsB = __int_as_float(e.y); }
            int nbM = max(nbA, nbB);
            int nt = (nbM + 3) >> 2;
            nt = (nt + 1) & ~1;           // even => unroll-2; nt<=16 so shfl idx <= 63
            for (int t = 0; t < nt; t += 2) {
                int l0 = 4 * t + g;
                int l1 = l0 + 4;
                int   sA0 = __shfl(idxA, l0); float fA0 = __shfl(dsA, l0);
                int   sA1 = __shfl(idxA, l1); float fA1 = __shfl(dsA, l1);
                int   sB0 = __shfl(idxB, l0); float fB0 = __shfl(dsB, l0);
                int   sB1 = __shfl(idxB, l1); float fB1 = __shfl(dsB, l1);
                uint2 rA0 = *(const uint2*)&Xcb[(size_t)sA0 * 64];
                uint2 rA1 = *(const uint2*)&Xcb[(size_t)sA1 * 64];
                uint2 rB0 = *(const uint2*)&Xcb[(size_t)sB0 * 64];
                uint2 rB1 = *(const uint2*)&Xcb[(size_t)sB1 * 64];
                acc4(aA, rA0, fA0);
                acc4(aA, rA1, fA1);
                acc4(aB, rB0, fB0);
                acc4(aB, rB1, fB1);
            }
        }
        // cross-group reduce (4 partial sums -> total)
#pragma unroll
        for (int i = 0; i < 4; ++i) {
            aA[i] += __shfl_xor(aA[i], 16); aA[i] += __shfl_xor(aA[i], 32);
            aB[i] += __shfl_xor(aB[i], 16); aB[i] += __shfl_xor(aB[i], 32);
        }
        // self-loop + outer dinv + bias + relu
        acc4(aA, srA, dvA);
        acc4(aB, srB, dvB);
        float4 h4A, h4B;
        h4A.x = fmaxf(fmaf(dvA, aA[0], bb4.x), 0.f);
        h4A.y = fmaxf(fmaf(dvA, aA[1], bb4.y), 0.f);
        h4A.z = fmaxf(fmaf(dvA, aA[2], bb4.z), 0.f);
        h4A.w = fmaxf(fmaf(dvA, aA[3], bb4.w), 0.f);
        h4B.x = fmaxf(fmaf(dvB, aB[0], bb4.x), 0.f);
        h4B.y = fmaxf(fmaf(dvB, aB[1], bb4.y), 0.f);
        h4B.z = fmaxf(fmaf(dvB, aB[2], bb4.z), 0.f);
        h4B.w = fmaxf(fmaf(dvB, aB[3], bb4.w), 0.f);
        // transpose to feature=lane via per-wave LDS
        if (g == 0) {
            *(float4*)&hb[wave][0][cb] = h4A;
            *(float4*)&hb[wave][1][cb] = h4B;
        }
        float hA = hb[wave][0][lane];
        float hB = hb[wave][1][lane];
        float yA = 0.f, yB = 0.f;
#pragma unroll 8
        for (int k = 0; k < 64; ++k) {
            float w = Wl[k * 64 + lane];
            yA = fmaf(__shfl(hA, k), w, yA);
            yB = fmaf(__shfl(hB, k), w, yB);
        }
        Y[(size_t)vA * 64 + lane] = __float2half(yA);
        if (hasB) Y[(size_t)vB * 64 + lane] = __float2half(yB);
    }
}

// ------- layer2 agg + MLP head (R2 structure, fp16 gather) -------

__global__ void agg_head_kernel(const __half* __restrict__ Yin, const int2* __restrict__ edges,
                                const int* __restrict__ rowptr, const int* __restrict__ counts,
                                const float* __restrict__ dinv, const float* __restrict__ b2,
                                const float* __restrict__ dW1, const float* __restrict__ db1,
                                const float* __restrict__ dW2, const float* __restrict__ db2,
                                float* __restrict__ out, int N) {
    __shared__ float D1[64 * 64];
    __shared__ float W2l[64 * 16];
    __shared__ float hb[4][2][64];
    int tid = threadIdx.x;
    for (int i = tid; i < 4096; i += 256) D1[i] = dW1[i];
    for (int i = tid; i < 1024; i += 256) W2l[i] = dW2[i];
    __syncthreads();
    int lane = tid & 63, wave = tid >> 6;
    int g = lane >> 4;
    int cb = (lane & 15) * 4;
    const __half* Ycb = Yin + cb;
    int c = lane & 15, part = lane >> 4;
    float4 bb4 = *(const float4*)&b2[cb];
    float bb1 = db1[lane];
    float ob  = db2[c];
    int NP = (N + 1) >> 1;
    int p0 = blockIdx.x * 4 + wave;
    int pstr = gridDim.x * 4;
    for (int p = p0; p < NP; p += pstr) {
        int vA = 2 * p, vB = 2 * p + 1;
        bool hasB = vB < N;
        int startA = __builtin_amdgcn_readfirstlane(rowptr[vA]);
        int cntA   = __builtin_amdgcn_readfirstlane(counts[vA]);
        int startB = hasB ? __builtin_amdgcn_readfirstlane(rowptr[vB]) : 0;
        int cntB   = hasB ? __builtin_amdgcn_readfirstlane(counts[vB]) : 0;
        float dvA = dinv[vA];
        float dvB = hasB ? dinv[vB] : 0.f;
        int vBs = hasB ? vB : vA;
        uint2 srA = *(const uint2*)&Ycb[(size_t)vA * 64];
        uint2 srB = *(const uint2*)&Ycb[(size_t)vBs * 64];
        float aA[4] = {0.f, 0.f, 0.f, 0.f};
        float aB[4] = {0.f, 0.f, 0.f, 0.f};
        int cntM = max(cntA, cntB);
        for (int base = 0; base < cntM; base += 64) {
            int nbA = min(64, cntA - base);
            int nbB = min(64, cntB - base);
            int idxA = 0, idxB = 0; float dsA = 0.f, dsB = 0.f;
            if (lane < nbA) { int2 e = edges[startA + base + lane]; idxA = e.x; dsA = __int_as_float(e.y); }
            if (lane < nbB) { int2 e = edges[startB + base + lane]; idxB = e.x; dsB = __int_as_float(e.y); }
            int nbM = max(nbA, nbB);
            int nt = (nbM + 3) >> 2;
            nt = (nt + 1) & ~1;
            for (int t = 0; t < nt; t += 2) {
                int l0 = 4 * t + g;
                int l1 = l0 + 4;
                int   sA0 = __shfl(idxA, l0); float fA0 = __shfl(dsA, l0);
                int   sA1 = __shfl(idxA, l1); float fA1 = __shfl(dsA, l1);
                int   sB0 = __shfl(idxB, l0); float fB0 = __shfl(dsB, l0);
                int   sB1 = __shfl(idxB, l1); float fB1 = __shfl(dsB, l1);
                uint2 rA0 = *(const uint2*)&Ycb[(size_t)sA0 * 64];
                uint2 rA1 = *(const uint2*)&Ycb[(size_t)sA1 * 64];
                uint2 rB0 = *(const uint2*)&Ycb[(size_t)sB0 * 64];
                uint2 rB1 = *(const uint2*)&Ycb[(size_t)sB1 * 64];
                acc4(aA, rA0, fA0);
                acc4(aA, rA1, fA1);
                acc4(aB, rB0, fB0);
                acc4(aB, rB1, fB1);
            }
        }
#pragma unroll
        for (int i = 0; i < 4; ++i) {
            aA[i] += __shfl_xor(aA[i], 16); aA[i] += __shfl_xor(aA[i], 32);
            aB[i] += __shfl_xor(aB[i], 16); aB[i] += __shfl_xor(aB[i], 32);
        }
        acc4(aA, srA, dvA);
        acc4(aB, srB, dvB);
        float4 h4A, h4B;
        h4A.x = fmaxf(fmaf(dvA, aA[0], bb4.x), 0.f);
        h4A.y = fmaxf(fmaf(dvA, aA[1], bb4.y), 0.f);
        h4A.z = fmaxf(fmaf(dvA, aA[2], bb4.z), 0.f);
        h4A.w = fmaxf(fmaf(dvA, aA[3], bb4.w), 0.f);
        h4B.x = fmaxf(fmaf(dvB, aB[0], bb4.x), 0.f);
        h4B.y = fmaxf(fmaf(dvB, aB[1], bb4.y), 0.f);
        h4B.z = fmaxf(fmaf(dvB, aB[2], bb4.z), 0.f);
        h4B.w = fmaxf(fmaf(dvB, aB[3], bb4.w), 0.f);
        if (g == 0) {
            *(float4*)&hb[wave][0][cb] = h4A;
            *(float4*)&hb[wave][1][cb] = h4B;
        }
        float hA = hb[wave][0][lane];
        float hB = hb[wave][1][lane];
        float aAv = bb1, aBv = bb1;
#pragma unroll 8
        for (int k = 0; k < 64; ++k) {
            float w = D1[k * 64 + lane];
            aAv = fmaf(__shfl(hA, k), w, aAv);
            aBv = fmaf(__shfl(hB, k), w, aBv);
        }
        aAv = fmaxf(aAv, 0.f); aBv = fmaxf(aBv, 0.f);
        float oA = 0.f, oB = 0.f;
#pragma unroll 8
        for (int kk = 0; kk < 16; ++kk) {
            float w = W2l[(part * 16 + kk) * 16 + c];
            oA = fmaf(__shfl(aAv, part * 16 + kk), w, oA);
            oB = fmaf(__shfl(aBv, part * 16 + kk), w, oB);
        }
        oA += __shfl_xor(oA, 16); oA += __shfl_xor(oA, 32);
        oB += __shfl_xor(oB, 16); oB += __shfl_xor(oB, 32);
        if (lane < 16) {
            out[(size_t)vA * 16 + lane] = oA + ob;
            if (hasB) out[(size_t)vB * 16 + lane] = oB + ob;
        }
    }
}

// ---------------- launch ----------------

extern "C" void kernel_launch(void* const* d_in, const int* in_sizes, int n_in,
                              void* d_out, int out_size, void* d_ws, size_t ws_size,
                              hipStream_t stream) {
    const float* x   = (const float*)d_in[0];
    const int*   ei  = (const int*)d_in[1];
    const float* W1  = (const float*)d_in[2];
    const float* b1  = (const float*)d_in[3];
    const float* W2  = (const float*)d_in[4];
    const float* b2  = (const float*)d_in[5];
    const float* dW1 = (const float*)d_in[6];
    const float* db1 = (const float*)d_in[7];
    const float* dW2 = (const float*)d_in[8];
    const float* db2 = (const float*)d_in[9];
    float* out = (float*)d_out;

    int N = in_sizes[0] / 64;
    int E = in_sizes[1] / 2;
    const int* src = ei;
    const int* dst = ei + E;

    size_t off = 0;
    auto alloc = [&](size_t bytes) {
        void* p = (char*)d_ws + off;
        off += (bytes + 511) & ~(size_t)511;
        return p;
    };
    int Npad = (N + 127) & ~127;
    int*    counts = (int*)alloc((size_t)Npad * 8);     // [counts | fillc]
    int*    fillc  = counts + Npad;
    int*    rowptr = (int*)alloc((size_t)N * 4);
    int*    bsums  = (int*)alloc(512 * 4);
    int2*   edges  = (int2*)alloc((size_t)E * 8);
    float*  dinv   = (float*)alloc((size_t)N * 4);
    __half* xw16   = (__half*)alloc((size_t)N * 64 * 2);
    __half* yw16   = (__half*)alloc((size_t)N * 64 * 2);

    hipMemsetAsync(counts, 0, (size_t)Npad * 8, stream);

    int nbN = (N + 255) / 256;
    int nbE = (E + 255) / 256;

    count_kernel<<<nbE, 256, 0, stream>>>(dst, counts, E);
    scan_local<<<nbN, 256, 0, stream>>>(counts, rowptr, bsums, dinv, N);
    scan_bsums<<<1, 512, 0, stream>>>(bsums, nbN);
    scan_add<<<nbN, 256, 0, stream>>>(rowptr, bsums, N);
    fill_kernel<<<nbE, 256, 0, stream>>>(src, dst, rowptr, fillc, dinv, edges, E);

    gemm64_kernel<<<4096, 128, 0, stream>>>(x, W1, xw16, N);
    agg_mm_kernel<<<2048, 256, 0, stream>>>(xw16, edges, rowptr, counts, dinv, b1, W2, yw16, N);
    agg_head_kernel<<<2048, 256, 0, stream>>>(yw16, edges, rowptr, counts, dinv, b2,
                                              dW1, db1, dW2, db2, out, N);
}